// Round 7
// baseline (419.460 us; speedup 1.0000x reference)
//
#include <hip/hip_runtime.h>

// GraphAttentionLayer, MI355X (gfx950). All fp32 in/out.
// out = 0.5 * softmax_row(cos(xn,yn) + (1-adj)*NEG) @ y + 0.5 * x
//
// R7: DENSE flash-style MFMA formulation. adj (256 MB) is the roofline
// (~43 us); all matmul work (2 x 34.4 GFLOP bf16) hides under the stream.
// - prepass: xhat = l2norm(x) bf16 [N,256]; yswz = l2norm(y) bf16, 64-row
//   tiles with 16B-unit XOR swizzle (u^=row&31) for conflict-free ds_read;
//   ytswz = bf16(y^T) in [jtile][256][64] tiles (u^=n&7). Note yhat*||y||=y,
//   so PV's operand is plain y transposed - no scale array needed.
// - main: block = 256 rows x 1024 j (8 j-chunks -> 256 blocks = 1/CU),
//   8 waves x 32 rows. Per 64-j step: stage next Y/Yt tiles (global_load_lds
//   16B, linear LDS, pre-swizzled source), adj via 32 coalesced 256B loads +
//   ballot -> per-lane u64 row mask; swapped QK^T (S^T = mfma(Yhat, Xhat));
//   mask+exp (shift = const 1.0, cos<=1); cvt_pk_bf16 + permlane32_swap
//   builds PV A-frags in-register (T12); PV mfma accumulates O.
// - epilogue: split-j partials (jc=0 -> d_out, rest -> ws) + Z partials;
//   zred + fin kernels combine: out = O/Z*0.5 + 0.5*x.

typedef short bf16x8 __attribute__((ext_vector_type(8)));
typedef float f32x16 __attribute__((ext_vector_type(16)));

static constexpr float EPSF = 1e-8f;
static constexpr float LOG2E = 1.44269504088896340736f;

__device__ __forceinline__ unsigned short f2bf(float f) {
    union { float f; unsigned int i; } v; v.f = f;
    return (unsigned short)((v.i + 0x7FFFu + ((v.i >> 16) & 1u)) >> 16);
}

// ---------- prepass: xhat (plain row-major normalized bf16) ----------
__global__ __launch_bounds__(256) void prep_x(const float* __restrict__ x,
                                              unsigned short* __restrict__ xhat, int N) {
    int row = (int)((blockIdx.x * blockDim.x + threadIdx.x) >> 6);
    int lane = threadIdx.x & 63;
    if (row >= N) return;
    float4 v = *(const float4*)(x + (size_t)row * 256 + lane * 4);
    float ss = v.x * v.x + v.y * v.y + v.z * v.z + v.w * v.w;
#pragma unroll
    for (int o = 1; o < 64; o <<= 1) ss += __shfl_xor(ss, o, 64);
    float inv = 1.0f / fmaxf(sqrtf(ss), EPSF);
    ushort4 b = { f2bf(v.x * inv), f2bf(v.y * inv), f2bf(v.z * inv), f2bf(v.w * inv) };
    *(ushort4*)(xhat + (size_t)row * 256 + lane * 4) = b;
}

// ---------- prepass: yswz (normalized, tiled+swizzled for QK^T A-frags) ----
__global__ __launch_bounds__(256) void prep_y(const float* __restrict__ y,
                                              char* __restrict__ yswz, int M) {
    int row = (int)((blockIdx.x * blockDim.x + threadIdx.x) >> 6);
    int lane = threadIdx.x & 63;
    if (row >= M) return;
    float4 v = *(const float4*)(y + (size_t)row * 256 + lane * 4);
    float ss = v.x * v.x + v.y * v.y + v.z * v.z + v.w * v.w;
#pragma unroll
    for (int o = 1; o < 64; o <<= 1) ss += __shfl_xor(ss, o, 64);
    float inv = 1.0f / fmaxf(sqrtf(ss), EPSF);
    int jt = row >> 6, r = row & 63;
    int u = lane >> 1, h = lane & 1;           // lane's float4 = half-unit (u,h)
    int phys = u ^ (r & 31);
    ushort4 b = { f2bf(v.x * inv), f2bf(v.y * inv), f2bf(v.z * inv), f2bf(v.w * inv) };
    *(ushort4*)(yswz + (size_t)jt * 32768 + r * 512 + phys * 16 + h * 8) = b;
}

// ---------- prepass: ytswz = bf16(y^T), [jtile][256 n][8 units] swizzled ----
__global__ __launch_bounds__(256) void prep_yt(const float* __restrict__ y,
                                               char* __restrict__ ytswz, int M) {
    int t = blockIdx.x * blockDim.x + threadIdx.x;
    int np = t & 255;
    int up = (t >> 8) & 7;
    int jt = t >> 11;
    if (jt >= (M >> 6)) return;
    const float* yb = y + (size_t)(jt * 64 + up * 8) * 256 + np;
    unsigned w0 = (unsigned)f2bf(yb[0])        | ((unsigned)f2bf(yb[256])  << 16);
    unsigned w1 = (unsigned)f2bf(yb[512])      | ((unsigned)f2bf(yb[768])  << 16);
    unsigned w2 = (unsigned)f2bf(yb[1024])     | ((unsigned)f2bf(yb[1280]) << 16);
    unsigned w3 = (unsigned)f2bf(yb[1536])     | ((unsigned)f2bf(yb[1792]) << 16);
    uint4 out = { w0, w1, w2, w3 };
    *(uint4*)(ytswz + (size_t)jt * 32768 + np * 128 + ((up ^ (np & 7)) << 4)) = out;
}

// ---------- main ----------
#define GLD16(gp, lp) __builtin_amdgcn_global_load_lds( \
    (const __attribute__((address_space(1))) unsigned int*)(gp), \
    (__attribute__((address_space(3))) unsigned int*)(lp), 16, 0, 0)

#define PKSWAP(E, TAU, W) { \
    unsigned X0, X1, Y0, Y1; \
    asm("v_cvt_pk_bf16_f32 %0, %1, %2" : "=v"(X0) : "v"(E[8*TAU+0]), "v"(E[8*TAU+1])); \
    asm("v_cvt_pk_bf16_f32 %0, %1, %2" : "=v"(X1) : "v"(E[8*TAU+2]), "v"(E[8*TAU+3])); \
    asm("v_cvt_pk_bf16_f32 %0, %1, %2" : "=v"(Y0) : "v"(E[8*TAU+4]), "v"(E[8*TAU+5])); \
    asm("v_cvt_pk_bf16_f32 %0, %1, %2" : "=v"(Y1) : "v"(E[8*TAU+6]), "v"(E[8*TAU+7])); \
    asm("v_permlane32_swap_b32 %0, %1" : "+v"(X0), "+v"(Y0)); \
    asm("v_permlane32_swap_b32 %0, %1" : "+v"(X1), "+v"(Y1)); \
    W[0] = X0; W[1] = X1; W[2] = Y0; W[3] = Y1; }

__global__ __launch_bounds__(512, 2) void gat_main(
        const unsigned short* __restrict__ xhat,
        const char* __restrict__ yswz,
        const char* __restrict__ ytswz,
        const float* __restrict__ adj,
        float* __restrict__ o0,     // jc==0 partial (d_out)
        float* __restrict__ ows,    // jc>=1 partials
        float* __restrict__ zpart,
        int N, int M, int TPB) {
    __shared__ __align__(16) char lds[131072];  // Y dbuf 2x32K | Yt dbuf 2x32K

    int tid = threadIdx.x;
    int w = tid >> 6, lane = tid & 63;
    int hi = lane >> 5, lm = lane & 31;
    int i0 = (int)blockIdx.x * 256;
    int jc = (int)blockIdx.y;
    int g0 = jc * TPB;

    // Q-frags: lane holds xhat[i0+w*32+lm][16*kt + 8*hi + 0..7]
    bf16x8 qf[16];
    {
        const char* qb = (const char*)xhat + (size_t)(i0 + w * 32 + lm) * 512 + hi * 16;
#pragma unroll
        for (int kt = 0; kt < 16; ++kt) qf[kt] = *(const bf16x8*)(qb + kt * 32);
    }

    f32x16 o[8];
#pragma unroll
    for (int nt = 0; nt < 8; ++nt) o[nt] = (f32x16)(0.0f);
    float z = 0.0f;

    // stage tile g into buffer b (linear LDS; source pre-swizzled)
    auto stage = [&](int g, int b) {
        const char* ys = yswz + (size_t)g * 32768;
        const char* ts = ytswz + (size_t)g * 32768;
        char* yd = lds + b * 32768;
        char* td = lds + 65536 + b * 32768;
#pragma unroll
        for (int c = 0; c < 4; ++c) {
            int lo = w * 4096 + c * 1024;        // wave-uniform LDS base
            int go = lo + lane * 16;             // per-lane global addr
            GLD16(ys + go, yd + lo);
            GLD16(ts + go, td + lo);
        }
    };

    stage(g0, 0);
    __syncthreads();

    for (int t = 0; t < TPB; ++t) {
        int buf = t & 1;
        if (t + 1 < TPB) stage(g0 + t + 1, buf ^ 1);

        // adj row masks: lane ends with u64 mask for row (i0+w*32+lm)
        unsigned long long mask = 0ull;
        {
            const float* ab = adj + (size_t)(i0 + w * 32) * M + (size_t)(g0 + t) * 64 + lane;
#pragma unroll 8
            for (int r = 0; r < 32; ++r) {
                float a = ab[(size_t)r * M];
                unsigned long long b = __ballot(a != 0.0f);
                if (lm == r) mask = b;
            }
        }

        // QK^T (swapped): S^T[jt*32+crow][lm] over K=256
        const char* yb = lds + buf * 32768;
        f32x16 s0 = (f32x16)(0.0f), s1 = (f32x16)(0.0f);
#pragma unroll
        for (int kt = 0; kt < 16; ++kt) {
            int phys = (hi + 2 * kt) ^ lm;
            bf16x8 a0 = *(const bf16x8*)(yb + lm * 512 + phys * 16);
            bf16x8 a1 = *(const bf16x8*)(yb + (32 + lm) * 512 + phys * 16);
            s0 = __builtin_amdgcn_mfma_f32_32x32x16_bf16(a0, qf[kt], s0, 0, 0, 0);
            s1 = __builtin_amdgcn_mfma_f32_32x32x16_bf16(a1, qf[kt], s1, 0, 0, 0);
        }

        // mask + exp(cos-1) + Z
        unsigned mw0 = (unsigned)mask, mw1 = (unsigned)(mask >> 32);
        float e0[16], e1[16];
        float zl = 0.0f;
#pragma unroll
        for (int rg = 0; rg < 16; ++rg) {
            int jl = (rg & 3) + 8 * (rg >> 2) + 4 * hi;
            float x0 = __builtin_exp2f(__builtin_fmaf(s0[rg], LOG2E, -LOG2E));
            float x1 = __builtin_exp2f(__builtin_fmaf(s1[rg], LOG2E, -LOG2E));
            e0[rg] = ((mw0 >> jl) & 1u) ? x0 : 0.0f;
            e1[rg] = ((mw1 >> jl) & 1u) ? x1 : 0.0f;
            zl += e0[rg] + e1[rg];
        }
        z += zl;

        // P -> PV A-frags in-register (cvt_pk + permlane32_swap)
        unsigned pw0[4], pw1[4], pw2[4], pw3[4];
        PKSWAP(e0, 0, pw0); PKSWAP(e0, 1, pw1);
        PKSWAP(e1, 0, pw2); PKSWAP(e1, 1, pw3);
        bf16x8 paf[4];
        { uint4 q = { pw0[0], pw0[1], pw0[2], pw0[3] }; paf[0] = __builtin_bit_cast(bf16x8, q); }
        { uint4 q = { pw1[0], pw1[1], pw1[2], pw1[3] }; paf[1] = __builtin_bit_cast(bf16x8, q); }
        { uint4 q = { pw2[0], pw2[1], pw2[2], pw2[3] }; paf[2] = __builtin_bit_cast(bf16x8, q); }
        { uint4 q = { pw3[0], pw3[1], pw3[2], pw3[3] }; paf[3] = __builtin_bit_cast(bf16x8, q); }

        // PV: O[m][n'] += P[m][k'] * yT[n'][k']
        const char* tb = lds + 65536 + buf * 32768;
#pragma unroll
        for (int nt = 0; nt < 8; ++nt) {
            int np = nt * 32 + lm;
#pragma unroll
            for (int tp = 0; tp < 4; ++tp) {
                int phys = (hi + 2 * tp) ^ (np & 7);
                bf16x8 bfr = *(const bf16x8*)(tb + np * 128 + phys * 16);
                o[nt] = __builtin_amdgcn_mfma_f32_32x32x16_bf16(paf[tp], bfr, o[nt], 0, 0, 0);
            }
        }

        __syncthreads();
    }

    // Z partial (lane pair hi/lo holds complementary j subsets)
    z += __shfl_xor(z, 32, 64);
    if (lane < 32) zpart[(size_t)jc * N + i0 + w * 32 + lane] = z;

    float* ob = (jc == 0) ? o0 : (ows + (size_t)(jc - 1) * N * 256);
#pragma unroll
    for (int nt = 0; nt < 8; ++nt) {
#pragma unroll
        for (int rg = 0; rg < 16; ++rg) {
            int m = (rg & 3) + 8 * (rg >> 2) + 4 * hi;
            ob[(size_t)(i0 + w * 32 + m) * 256 + nt * 32 + lm] = o[nt][rg];
        }
    }
}

// ---------- reductions ----------
__global__ __launch_bounds__(256) void zred(const float* __restrict__ zpart,
                                            float* __restrict__ zinv, int N, int js) {
    int i = blockIdx.x * 256 + threadIdx.x;
    if (i >= N) return;
    float s = 0.0f;
    for (int jc = 0; jc < js; ++jc) s += zpart[(size_t)jc * N + i];
    zinv[i] = 0.5f / s;
}

__global__ __launch_bounds__(256) void fin(float* __restrict__ out,
                                           const float* __restrict__ ows,
                                           const float* __restrict__ zinv,
                                           const float* __restrict__ x,
                                           int N, int js) {
    int gid = blockIdx.x * 256 + threadIdx.x;     // one float4 each
    if (gid >= N * 64) return;
    int i = gid >> 6;
    float4 a = ((const float4*)out)[gid];
    for (int jc = 1; jc < js; ++jc) {
        float4 p = ((const float4*)(ows + (size_t)(jc - 1) * N * 256))[gid];
        a.x += p.x; a.y += p.y; a.z += p.z; a.w += p.w;
    }
    float zi = zinv[i];
    float4 xv = ((const float4*)x)[gid];
    float4 r;
    r.x = a.x * zi + 0.5f * xv.x;
    r.y = a.y * zi + 0.5f * xv.y;
    r.z = a.z * zi + 0.5f * xv.z;
    r.w = a.w * zi + 0.5f * xv.w;
    ((float4*)out)[gid] = r;
}

extern "C" void kernel_launch(void* const* d_in, const int* in_sizes, int n_in,
                              void* d_out, int out_size, void* d_ws, size_t ws_size,
                              hipStream_t stream) {
    const float* x = (const float*)d_in[0];
    const float* y = (const float*)d_in[1];
    const float* adj = (const float*)d_in[2];
    float* out = (float*)d_out;

    const int D = 256;
    int N = in_sizes[0] / D;
    int M = in_sizes[1] / D;

    char* w = (char*)d_ws;
    unsigned short* xhat = (unsigned short*)w;                       // N*512 B
    char* yswz  = w + (size_t)N * 512;                               // M*512 B
    char* ytswz = w + (size_t)N * 512 + (size_t)M * 512;             // M*512 B
    size_t base = (size_t)N * 512 + 2 * (size_t)M * 512;

    int js = 1;
    {
        int cands[3] = { 8, 4, 2 };
        for (int k = 0; k < 3; ++k) {
            int c = cands[k];
            size_t need = base + (size_t)(c + 1) * N * 4 +           // zpart + zinv
                          (size_t)(c - 1) * N * 1024;                // O partials
            if (ws_size >= need) { js = c; break; }
        }
    }
    float* zpart = (float*)(w + base);
    float* zinv  = zpart + (size_t)js * N;
    float* ows   = zinv + N;
    int TPB = (M / 64) / js;

    prep_x<<<(N + 3) / 4, 256, 0, stream>>>(x, xhat, N);
    prep_y<<<(M + 3) / 4, 256, 0, stream>>>(y, yswz, M);
    prep_yt<<<((M / 64) * 2048 + 255) / 256, 256, 0, stream>>>(y, ytswz, M);
    gat_main<<<dim3(N / 256, js), 512, 0, stream>>>(xhat, yswz, ytswz, adj,
                                                    out, ows, zpart, N, M, TPB);
    zred<<<(N + 255) / 256, 256, 0, stream>>>(zpart, zinv, N, js);
    fin<<<(N * 64 + 255) / 256, 256, 0, stream>>>(out, ows, zinv, x, N, js);
}

// Round 8
// 292.500 us; speedup vs baseline: 1.4341x; 1.4341x over previous
//
#include <hip/hip_runtime.h>

// GraphAttentionLayer, MI355X (gfx950). All fp32 in/out.
// out = 0.5 * softmax_row(cos(xn,yn) + (1-adj)*NEG) @ y + 0.5 * x
//
// R8 = R7 (dense flash-MFMA, verified correct: absmax == sparse versions)
// with ONE change: the adj mask is no longer built via 32 serial
// {load -> __ballot} iterations (convergent ops defeated load pipelining ->
// ~29K cyc/tile stall). Each lane now reads its own row's 32 columns as
// 8 plain float4 loads, split in two halves interleaved with the QK^T
// MFMA loop (latency hidden), packs bits locally, and one shfl_xor(32)
// assembles the full 64-bit row mask. Stage issue moved after the packs.

typedef short bf16x8 __attribute__((ext_vector_type(8)));
typedef float f32x16 __attribute__((ext_vector_type(16)));

static constexpr float EPSF = 1e-8f;
static constexpr float LOG2E = 1.44269504088896340736f;

__device__ __forceinline__ unsigned short f2bf(float f) {
    union { float f; unsigned int i; } v; v.f = f;
    return (unsigned short)((v.i + 0x7FFFu + ((v.i >> 16) & 1u)) >> 16);
}

// ---------- prepass: xhat (plain row-major normalized bf16) ----------
__global__ __launch_bounds__(256) void prep_x(const float* __restrict__ x,
                                              unsigned short* __restrict__ xhat, int N) {
    int row = (int)((blockIdx.x * blockDim.x + threadIdx.x) >> 6);
    int lane = threadIdx.x & 63;
    if (row >= N) return;
    float4 v = *(const float4*)(x + (size_t)row * 256 + lane * 4);
    float ss = v.x * v.x + v.y * v.y + v.z * v.z + v.w * v.w;
#pragma unroll
    for (int o = 1; o < 64; o <<= 1) ss += __shfl_xor(ss, o, 64);
    float inv = 1.0f / fmaxf(sqrtf(ss), EPSF);
    ushort4 b = { f2bf(v.x * inv), f2bf(v.y * inv), f2bf(v.z * inv), f2bf(v.w * inv) };
    *(ushort4*)(xhat + (size_t)row * 256 + lane * 4) = b;
}

// ---------- prepass: yswz (normalized, tiled+swizzled for QK^T A-frags) ----
__global__ __launch_bounds__(256) void prep_y(const float* __restrict__ y,
                                              char* __restrict__ yswz, int M) {
    int row = (int)((blockIdx.x * blockDim.x + threadIdx.x) >> 6);
    int lane = threadIdx.x & 63;
    if (row >= M) return;
    float4 v = *(const float4*)(y + (size_t)row * 256 + lane * 4);
    float ss = v.x * v.x + v.y * v.y + v.z * v.z + v.w * v.w;
#pragma unroll
    for (int o = 1; o < 64; o <<= 1) ss += __shfl_xor(ss, o, 64);
    float inv = 1.0f / fmaxf(sqrtf(ss), EPSF);
    int jt = row >> 6, r = row & 63;
    int u = lane >> 1, h = lane & 1;           // lane's float4 = half-unit (u,h)
    int phys = u ^ (r & 31);
    ushort4 b = { f2bf(v.x * inv), f2bf(v.y * inv), f2bf(v.z * inv), f2bf(v.w * inv) };
    *(ushort4*)(yswz + (size_t)jt * 32768 + r * 512 + phys * 16 + h * 8) = b;
}

// ---------- prepass: ytswz = bf16(y^T), [jtile][256 n][8 units] swizzled ----
__global__ __launch_bounds__(256) void prep_yt(const float* __restrict__ y,
                                               char* __restrict__ ytswz, int M) {
    int t = blockIdx.x * blockDim.x + threadIdx.x;
    int np = t & 255;
    int up = (t >> 8) & 7;
    int jt = t >> 11;
    if (jt >= (M >> 6)) return;
    const float* yb = y + (size_t)(jt * 64 + up * 8) * 256 + np;
    unsigned w0 = (unsigned)f2bf(yb[0])        | ((unsigned)f2bf(yb[256])  << 16);
    unsigned w1 = (unsigned)f2bf(yb[512])      | ((unsigned)f2bf(yb[768])  << 16);
    unsigned w2 = (unsigned)f2bf(yb[1024])     | ((unsigned)f2bf(yb[1280]) << 16);
    unsigned w3 = (unsigned)f2bf(yb[1536])     | ((unsigned)f2bf(yb[1792]) << 16);
    uint4 out = { w0, w1, w2, w3 };
    *(uint4*)(ytswz + (size_t)jt * 32768 + np * 128 + ((up ^ (np & 7)) << 4)) = out;
}

// ---------- main ----------
#define GLD16(gp, lp) __builtin_amdgcn_global_load_lds( \
    (const __attribute__((address_space(1))) unsigned int*)(gp), \
    (__attribute__((address_space(3))) unsigned int*)(lp), 16, 0, 0)

#define PKSWAP(E, TAU, W) { \
    unsigned X0, X1, Y0, Y1; \
    asm("v_cvt_pk_bf16_f32 %0, %1, %2" : "=v"(X0) : "v"(E[8*TAU+0]), "v"(E[8*TAU+1])); \
    asm("v_cvt_pk_bf16_f32 %0, %1, %2" : "=v"(X1) : "v"(E[8*TAU+2]), "v"(E[8*TAU+3])); \
    asm("v_cvt_pk_bf16_f32 %0, %1, %2" : "=v"(Y0) : "v"(E[8*TAU+4]), "v"(E[8*TAU+5])); \
    asm("v_cvt_pk_bf16_f32 %0, %1, %2" : "=v"(Y1) : "v"(E[8*TAU+6]), "v"(E[8*TAU+7])); \
    asm("v_permlane32_swap_b32 %0, %1" : "+v"(X0), "+v"(Y0)); \
    asm("v_permlane32_swap_b32 %0, %1" : "+v"(X1), "+v"(Y1)); \
    W[0] = X0; W[1] = X1; W[2] = Y0; W[3] = Y1; }

#define PACKB(AQ, BASE) \
    mb |= (AQ.x != 0.0f ? 1u : 0u) << (BASE); \
    mb |= (AQ.y != 0.0f ? 1u : 0u) << ((BASE) + 1); \
    mb |= (AQ.z != 0.0f ? 1u : 0u) << ((BASE) + 2); \
    mb |= (AQ.w != 0.0f ? 1u : 0u) << ((BASE) + 3);

__global__ __launch_bounds__(512, 2) void gat_main(
        const unsigned short* __restrict__ xhat,
        const char* __restrict__ yswz,
        const char* __restrict__ ytswz,
        const float* __restrict__ adj,
        float* __restrict__ o0,     // jc==0 partial (d_out)
        float* __restrict__ ows,    // jc>=1 partials
        float* __restrict__ zpart,
        int N, int M, int TPB) {
    __shared__ __align__(16) char lds[131072];  // Y dbuf 2x32K | Yt dbuf 2x32K

    int tid = threadIdx.x;
    int w = tid >> 6, lane = tid & 63;
    int hi = lane >> 5, lm = lane & 31;
    int i0 = (int)blockIdx.x * 256;
    int jc = (int)blockIdx.y;
    int g0 = jc * TPB;

    // Q-frags: lane holds xhat[i0+w*32+lm][16*kt + 8*hi + 0..7]
    bf16x8 qf[16];
    {
        const char* qb = (const char*)xhat + (size_t)(i0 + w * 32 + lm) * 512 + hi * 16;
#pragma unroll
        for (int kt = 0; kt < 16; ++kt) qf[kt] = *(const bf16x8*)(qb + kt * 32);
    }

    f32x16 o[8];
#pragma unroll
    for (int nt = 0; nt < 8; ++nt) o[nt] = (f32x16)(0.0f);
    float z = 0.0f;

    // stage tile g into buffer b (linear LDS; source pre-swizzled)
    auto stage = [&](int g, int b) {
        const char* ys = yswz + (size_t)g * 32768;
        const char* ts = ytswz + (size_t)g * 32768;
        char* yd = lds + b * 32768;
        char* td = lds + 65536 + b * 32768;
#pragma unroll
        for (int c = 0; c < 4; ++c) {
            int lo = w * 4096 + c * 1024;        // wave-uniform LDS base
            int go = lo + lane * 16;             // per-lane global addr
            GLD16(ys + go, yd + lo);
            GLD16(ts + go, td + lo);
        }
    };

    stage(g0, 0);
    __syncthreads();

    // per-lane adj base: own row (lm), own column half (hi)
    const float* abase = adj + (size_t)(i0 + w * 32 + lm) * M + hi * 32;

    for (int t = 0; t < TPB; ++t) {
        int buf = t & 1;
        const float* ab = abase + (size_t)(g0 + t) * 64;
        const char* yb = lds + buf * 32768;

        f32x16 s0 = (f32x16)(0.0f), s1 = (f32x16)(0.0f);
        unsigned mb = 0;

        // adj half 0 (cols hi*32 + 0..15): issue before QK^T kt 0..7
        {
            float4 A0 = *(const float4*)(ab + 0);
            float4 A1 = *(const float4*)(ab + 4);
            float4 A2 = *(const float4*)(ab + 8);
            float4 A3 = *(const float4*)(ab + 12);
#pragma unroll
            for (int kt = 0; kt < 8; ++kt) {
                int phys = (hi + 2 * kt) ^ lm;
                bf16x8 a0 = *(const bf16x8*)(yb + lm * 512 + phys * 16);
                bf16x8 a1 = *(const bf16x8*)(yb + (32 + lm) * 512 + phys * 16);
                s0 = __builtin_amdgcn_mfma_f32_32x32x16_bf16(a0, qf[kt], s0, 0, 0, 0);
                s1 = __builtin_amdgcn_mfma_f32_32x32x16_bf16(a1, qf[kt], s1, 0, 0, 0);
            }
            PACKB(A0, 0) PACKB(A1, 4) PACKB(A2, 8) PACKB(A3, 12)
        }
        // adj half 1 (cols hi*32 + 16..31): issue before QK^T kt 8..15
        {
            float4 A0 = *(const float4*)(ab + 16);
            float4 A1 = *(const float4*)(ab + 20);
            float4 A2 = *(const float4*)(ab + 24);
            float4 A3 = *(const float4*)(ab + 28);
#pragma unroll
            for (int kt = 8; kt < 16; ++kt) {
                int phys = (hi + 2 * kt) ^ lm;
                bf16x8 a0 = *(const bf16x8*)(yb + lm * 512 + phys * 16);
                bf16x8 a1 = *(const bf16x8*)(yb + (32 + lm) * 512 + phys * 16);
                s0 = __builtin_amdgcn_mfma_f32_32x32x16_bf16(a0, qf[kt], s0, 0, 0, 0);
                s1 = __builtin_amdgcn_mfma_f32_32x32x16_bf16(a1, qf[kt], s1, 0, 0, 0);
            }
            PACKB(A0, 16) PACKB(A1, 20) PACKB(A2, 24) PACKB(A3, 28)
        }

        // build full 64-bit row mask: mb holds cols hi*32..+31 of row lm
        unsigned other = __shfl_xor(mb, 32, 64);
        unsigned mw0 = hi ? other : mb;      // cols 0..31
        unsigned mw1 = hi ? mb : other;      // cols 32..63

        // mask + exp(cos-1) + Z, in place into s0/s1
        float zl = 0.0f;
#pragma unroll
        for (int rg = 0; rg < 16; ++rg) {
            int jl = (rg & 3) + 8 * (rg >> 2) + 4 * hi;
            float x0 = __builtin_exp2f(__builtin_fmaf(s0[rg], LOG2E, -LOG2E));
            float x1 = __builtin_exp2f(__builtin_fmaf(s1[rg], LOG2E, -LOG2E));
            s0[rg] = ((mw0 >> jl) & 1u) ? x0 : 0.0f;
            s1[rg] = ((mw1 >> jl) & 1u) ? x1 : 0.0f;
            zl += s0[rg] + s1[rg];
        }
        z += zl;

        // P -> PV A-frags in-register (cvt_pk + permlane32_swap)
        unsigned pw0[4], pw1[4], pw2[4], pw3[4];
        PKSWAP(s0, 0, pw0); PKSWAP(s0, 1, pw1);
        PKSWAP(s1, 0, pw2); PKSWAP(s1, 1, pw3);
        bf16x8 paf[4];
        { uint4 q = { pw0[0], pw0[1], pw0[2], pw0[3] }; paf[0] = __builtin_bit_cast(bf16x8, q); }
        { uint4 q = { pw1[0], pw1[1], pw1[2], pw1[3] }; paf[1] = __builtin_bit_cast(bf16x8, q); }
        { uint4 q = { pw2[0], pw2[1], pw2[2], pw2[3] }; paf[2] = __builtin_bit_cast(bf16x8, q); }
        { uint4 q = { pw3[0], pw3[1], pw3[2], pw3[3] }; paf[3] = __builtin_bit_cast(bf16x8, q); }

        // stage next tile now: drain at the end-of-iteration barrier only
        // has to cover the PV phase (~1.5-2K cyc), not the whole tile
        if (t + 1 < TPB) stage(g0 + t + 1, buf ^ 1);

        // PV: O[m][n'] += P[m][k'] * yT[n'][k']
        const char* tb = lds + 65536 + buf * 32768;
#pragma unroll
        for (int nt = 0; nt < 8; ++nt) {
            int np = nt * 32 + lm;
#pragma unroll
            for (int tp = 0; tp < 4; ++tp) {
                int phys = (hi + 2 * tp) ^ (np & 7);
                bf16x8 bfr = *(const bf16x8*)(tb + np * 128 + phys * 16);
                o[nt] = __builtin_amdgcn_mfma_f32_32x32x16_bf16(paf[tp], bfr, o[nt], 0, 0, 0);
            }
        }

        __syncthreads();
    }

    // Z partial (lane pair hi/lo holds complementary j subsets)
    z += __shfl_xor(z, 32, 64);
    if (lane < 32) zpart[(size_t)jc * N + i0 + w * 32 + lane] = z;

    float* ob = (jc == 0) ? o0 : (ows + (size_t)(jc - 1) * N * 256);
#pragma unroll
    for (int nt = 0; nt < 8; ++nt) {
#pragma unroll
        for (int rg = 0; rg < 16; ++rg) {
            int m = (rg & 3) + 8 * (rg >> 2) + 4 * hi;
            ob[(size_t)(i0 + w * 32 + m) * 256 + nt * 32 + lm] = o[nt][rg];
        }
    }
}

// ---------- reductions ----------
__global__ __launch_bounds__(256) void zred(const float* __restrict__ zpart,
                                            float* __restrict__ zinv, int N, int js) {
    int i = blockIdx.x * 256 + threadIdx.x;
    if (i >= N) return;
    float s = 0.0f;
    for (int jc = 0; jc < js; ++jc) s += zpart[(size_t)jc * N + i];
    zinv[i] = 0.5f / s;
}

__global__ __launch_bounds__(256) void fin(float* __restrict__ out,
                                           const float* __restrict__ ows,
                                           const float* __restrict__ zinv,
                                           const float* __restrict__ x,
                                           int N, int js) {
    int gid = blockIdx.x * 256 + threadIdx.x;     // one float4 each
    if (gid >= N * 64) return;
    int i = gid >> 6;
    float4 a = ((const float4*)out)[gid];
    for (int jc = 1; jc < js; ++jc) {
        float4 p = ((const float4*)(ows + (size_t)(jc - 1) * N * 256))[gid];
        a.x += p.x; a.y += p.y; a.z += p.z; a.w += p.w;
    }
    float zi = zinv[i];
    float4 xv = ((const float4*)x)[gid];
    float4 r;
    r.x = a.x * zi + 0.5f * xv.x;
    r.y = a.y * zi + 0.5f * xv.y;
    r.z = a.z * zi + 0.5f * xv.z;
    r.w = a.w * zi + 0.5f * xv.w;
    ((float4*)out)[gid] = r;
}

extern "C" void kernel_launch(void* const* d_in, const int* in_sizes, int n_in,
                              void* d_out, int out_size, void* d_ws, size_t ws_size,
                              hipStream_t stream) {
    const float* x = (const float*)d_in[0];
    const float* y = (const float*)d_in[1];
    const float* adj = (const float*)d_in[2];
    float* out = (float*)d_out;

    const int D = 256;
    int N = in_sizes[0] / D;
    int M = in_sizes[1] / D;

    char* w = (char*)d_ws;
    unsigned short* xhat = (unsigned short*)w;                       // N*512 B
    char* yswz  = w + (size_t)N * 512;                               // M*512 B
    char* ytswz = w + (size_t)N * 512 + (size_t)M * 512;             // M*512 B
    size_t base = (size_t)N * 512 + 2 * (size_t)M * 512;

    int js = 1;
    {
        int cands[3] = { 8, 4, 2 };
        for (int k = 0; k < 3; ++k) {
            int c = cands[k];
            size_t need = base + (size_t)(c + 1) * N * 4 +           // zpart + zinv
                          (size_t)(c - 1) * N * 1024;                // O partials
            if (ws_size >= need) { js = c; break; }
        }
    }
    float* zpart = (float*)(w + base);
    float* zinv  = zpart + (size_t)js * N;
    float* ows   = zinv + N;
    int TPB = (M / 64) / js;

    prep_x<<<(N + 3) / 4, 256, 0, stream>>>(x, xhat, N);
    prep_y<<<(M + 3) / 4, 256, 0, stream>>>(y, yswz, M);
    prep_yt<<<((M / 64) * 2048 + 255) / 256, 256, 0, stream>>>(y, ytswz, M);
    gat_main<<<dim3(N / 256, js), 512, 0, stream>>>(xhat, yswz, ytswz, adj,
                                                    out, ows, zpart, N, M, TPB);
    zred<<<(N + 255) / 256, 256, 0, stream>>>(zpart, zinv, N, js);
    fin<<<(N * 64 + 255) / 256, 256, 0, stream>>>(out, ows, zinv, x, N, js);
}